// Round 5
// baseline (169.849 us; speedup 1.0000x reference)
//
#include <hip/hip_runtime.h>
#include <hip/hip_cooperative_groups.h>

namespace cg = cooperative_groups;

#define N 512
#define TOPK 153
#define KP 160
#define D 64
#define NB 32          // batches
#define BN (NB*N)
#define EPSF 1e-8f
#define GRID 256
#define BLK 512

// ---------------- ws layout (bytes) ----------------
// 0x100000: G    u64[N*8]        (32KB)  gated selection bitmask (target-major)
// 0x108000: nbm  u64[N*8]        (32KB)  symmetrized adjacency + self
// 0x110000: idxl i32[N*KP]       (320KB) top-k source ids per target (rank order)
// 0x160000: wgtl f32[N*KP]       (320KB) c^2 * rs_i  (row-scaled structural coeff)
// 0x1B0000: rs   f32[N]          1/sqrt(sum_k c_ik^2)   [max_common cancels]
// 0x1C0000: h    f32[BN*D]       (4MB)

union SMem {
    float4 hs4[8192];                                 // 128KB  phase E: h[b]
    struct {                                          // phase A (front), 2 rows
        float cr[2][N];
        float q2[2][N];
        float ri[2][D];
        unsigned long long gb[2][8];
    } a;
    struct { float Ws[64*64]; float xs[32*64]; } d;   // 24KB   phase D (h GEMM)
    struct {                                          // phase C (edge weights)
        unsigned long long ni[2][8];
        float red[2][4];
        float rsb[2];
    } c;
};

// One cooperative kernel, 256 blocks x 512 threads, 1 block/CU (128KB LDS).
// 4 serialized dispatches (~6-10us each boundary) -> 3 grid.sync().
__global__ __launch_bounds__(BLK)
void k_all(const float* __restrict__ x, const float* __restrict__ W,
           const float* __restrict__ bias, const float* __restrict__ emb,
           float* __restrict__ out,
           unsigned long long* __restrict__ G, unsigned long long* __restrict__ nbm,
           int* __restrict__ idxl, float* __restrict__ wgtl,
           float* __restrict__ rs, float* __restrict__ h) {
    __shared__ SMem sm;
    cg::grid_group grid = cg::this_grid();
    int bid = blockIdx.x, t = threadIdx.x;
    int tt = t & 255, half = t >> 8;

    // ---------------- Phase A: norms + cosine + exact top-k (2 rows/block) ----
    {
        int i = bid*2 + half;
        if (tt < 16) ((float4*)sm.a.ri[half])[tt] = ((const float4*)(emb + i*D))[tt];
        if (tt < 8) sm.a.gb[half][tt] = 0ull;
        __syncthreads();
        // dot(i,j) and |j|^2 in one coalesced pass
        for (int j = tt; j < N; j += 256) {
            const float4* rj = (const float4*)(emb + j*D);
            float dot = 0.f, nsq = 0.f;
            #pragma unroll
            for (int q = 0; q < 16; ++q) {
                float4 v = rj[q];
                float4 u = ((const float4*)sm.a.ri[half])[q];   // LDS broadcast
                dot = fmaf(u.x,v.x,fmaf(u.y,v.y,fmaf(u.z,v.z,fmaf(u.w,v.w,dot))));
                nsq = fmaf(v.x,v.x,fmaf(v.y,v.y,fmaf(v.z,v.z,fmaf(v.w,v.w,nsq))));
            }
            sm.a.cr[half][j] = dot; sm.a.q2[half][j] = nsq;
        }
        __syncthreads();
        float ni = sqrtf(sm.a.q2[half][i & (N-1)]);
        for (int j = tt; j < N; j += 256)
            sm.a.cr[half][j] = sm.a.cr[half][j] / (ni*sqrtf(sm.a.q2[half][j]) + EPSF);
        __syncthreads();
        // exact top-k by rank counting (jax.lax.top_k tie semantics)
        for (int jj = tt; jj < N; jj += 256) {
            float v = sm.a.cr[half][jj];
            int rank = 0;
            #pragma unroll 8
            for (int m = 0; m < N; ++m) {
                float u = sm.a.cr[half][m];                     // LDS broadcast
                rank += (u > v) || (u == v && m < jj);
            }
            if (rank < TOPK) {
                idxl[i*KP + rank] = jj;            // rank order == ref order
                atomicOr(&sm.a.gb[half][jj>>6], 1ull << (jj&63));
            }
        }
        __syncthreads();
        if (tt < 8) G[i*8+tt] = sm.a.gb[half][tt];
    }
    __syncthreads();                               // LDS handoff A -> D

    // ---------------- Phase D: h = x @ W (64 rows/block) ----------------------
    {
        for (int e = t; e < 1024; e += BLK) ((float4*)sm.d.Ws)[e] = ((const float4*)W)[e];
        #pragma unroll
        for (int p = 0; p < 2; ++p) {
            int r0 = bid*64 + p*32;
            __syncthreads();                       // Ws ready / xs safe to overwrite
            ((float4*)sm.d.xs)[t] = ((const float4*)(x + r0*64))[t];  // 32 rows
            __syncthreads();
            int row = t >> 4, f0 = (t & 15)*4;
            float ax=0, ay=0, az=0, aw=0;
            #pragma unroll 8
            for (int cc = 0; cc < 64; ++cc) {
                float xv = sm.d.xs[row*64+cc];                  // broadcast
                float4 wv = *(const float4*)&sm.d.Ws[cc*64+f0]; // 2-way max
                ax = fmaf(xv,wv.x,ax); ay = fmaf(xv,wv.y,ay);
                az = fmaf(xv,wv.z,az); aw = fmaf(xv,wv.w,aw);
            }
            float4 o; o.x=ax; o.y=ay; o.z=az; o.w=aw;
            ((float4*)(h + r0*64))[t] = o;
        }
    }
    grid.sync();                                   // G complete, h complete

    // ---------------- Phase B: symmetrize adjacency (+self) -------------------
    if (bid < 64 && t < 64) {
        int tid = bid*64 + t;                      // 4096 total
        int a = tid >> 3, w = tid & 7;
        unsigned long long v = G[a*8+w];           // edges where a is target
        int aw = a >> 6, ab = a & 63;
        for (int bit = 0; bit < 64; ++bit) {       // transpose: a as source
            int b = (w<<6) | bit;
            v |= ((G[b*8 + aw] >> ab) & 1ull) << bit;
        }
        if (aw == w) v |= 1ull << ab;              // self loop
        nbm[a*8+w] = v;
    }
    grid.sync();                                   // nbm complete

    // ---------------- Phase C: per-edge popcount weights (2 rows/block) -------
    {
        int i = bid*2 + half, k = tt;
        if (k < 8) sm.c.ni[half][k] = nbm[i*8+k];
        __syncthreads();
        float c2 = 0.f;
        if (k < TOPK) {
            int j = idxl[i*KP+k];
            const ulonglong2* nj = (const ulonglong2*)(nbm + j*8);
            int c = 0;
            #pragma unroll
            for (int w = 0; w < 4; ++w) {
                ulonglong2 v = nj[w];
                c += __popcll(sm.c.ni[half][2*w] & v.x) + __popcll(sm.c.ni[half][2*w+1] & v.y);
            }
            c2 = (float)(c*c);                     // edge always has c>=2
        }
        float s = c2;
        #pragma unroll
        for (int o = 32; o > 0; o >>= 1) s += __shfl_down(s, o, 64);
        if ((k & 63) == 0) sm.c.red[half][k>>6] = s;
        __syncthreads();
        if (k == 0) {
            float deg = sm.c.red[half][0]+sm.c.red[half][1]+sm.c.red[half][2]+sm.c.red[half][3];
            float r = (float)(1.0/sqrt((double)deg));
            sm.c.rsb[half] = r;
            rs[i] = r;
        }
        __syncthreads();
        if (k < TOPK) wgtl[i*KP+k] = c2 * sm.c.rsb[half];
    }
    grid.sync();                                   // wgtl, rs complete

    // ---------------- Phase E: aggregate (block = chunk x batch) --------------
    {
        int b = bid & 31, chunk = bid >> 5;
        const float4* hb = (const float4*)h + b*8192;
        for (int e = t; e < 8192; e += BLK) sm.hs4[e] = hb[e];
        int lane = t & 63, wv = t >> 6;
        int ts = lane >> 4, fq = lane & 15;
        int tl = wv*4 + ts;                        // local target 0..31
        float4 bv = ((const float4*)bias)[fq];
        __syncthreads();
        #pragma unroll
        for (int grp = 0; grp < 2; ++grp) {
            int ti = chunk*64 + grp*32 + tl;
            const int*   ip = &idxl[ti*KP];
            const float* wp = &wgtl[ti*KP];
            float ax=0, ay=0, az=0, aw=0;
            #pragma unroll 4
            for (int kk = 0; kk < TOPK; ++kk) {
                int j = ip[kk];
                float w = wp[kk] * rs[j];
                float4 hv = sm.hs4[j*16 + fq];
                ax = fmaf(w,hv.x,ax); ay = fmaf(w,hv.y,ay);
                az = fmaf(w,hv.z,az); aw = fmaf(w,hv.w,aw);
            }
            float4 o; o.x = ax+bv.x; o.y = ay+bv.y; o.z = az+bv.z; o.w = aw+bv.w;
            ((float4*)out)[(b*512 + ti)*16 + fq] = o;
        }
    }
}

extern "C" void kernel_launch(void* const* d_in, const int* in_sizes, int n_in,
                              void* d_out, int out_size, void* d_ws, size_t ws_size,
                              hipStream_t stream) {
    const float* x    = (const float*)d_in[0];   // [32,512,64]
    const float* W    = (const float*)d_in[1];   // [64,64]
    const float* bias = (const float*)d_in[2];   // [64]
    const float* emb  = (const float*)d_in[3];   // [512,64]
    float* out = (float*)d_out;

    char* ws = (char*)d_ws;
    unsigned long long* G   = (unsigned long long*)(ws + 0x100000);
    unsigned long long* nbm = (unsigned long long*)(ws + 0x108000);
    int*   idxl = (int*)(ws + 0x110000);
    float* wgtl = (float*)(ws + 0x160000);
    float* rs   = (float*)(ws + 0x1B0000);
    float* h    = (float*)(ws + 0x1C0000);

    void* args[] = { (void*)&x, (void*)&W, (void*)&bias, (void*)&emb, (void*)&out,
                     (void*)&G, (void*)&nbm, (void*)&idxl, (void*)&wgtl,
                     (void*)&rs, (void*)&h };
    hipLaunchCooperativeKernel((void*)k_all, dim3(GRID), dim3(BLK), args, 0, stream);
}

// Round 6
// 91.703 us; speedup vs baseline: 1.8522x; 1.8522x over previous
//
#include <hip/hip_runtime.h>

#define N 512
#define TOPK 153
#define KP 160
#define D 64
#define NB 32          // batches
#define BN (NB*N)
#define EPSF 1e-8f

// ---------------- ws layout (bytes) ----------------
// 0x100000: G    u64[N*8]        (32KB)  gated selection bitmask (target-major)
// 0x108000: GT   u64[N*8]        (32KB)  transpose bitmask (built via atomicOr)
// 0x110000: idxl i32[N*KP]       (320KB) top-k source ids per target (rank order)
// 0x160000: wgtl f32[N*KP]       (320KB) c^2 * rs_i  (row-scaled structural coeff)
// 0x1B0000: rs   f32[N]          1/sqrt(sum_k c_ik^2)   [max_common cancels]
// 0x1C0000: h    f32[BN*D]       (4MB)

union SMem {
    struct {                     // front blocks (~4.4KB)
        float cr[N];
        float q2[N];
        float ri[D];
        unsigned long long gb[8];
    } f;
    struct { float xs[16*64]; float Ws[64*64]; } g;   // GEMM blocks (20KB)
};

// blocks 0..511: norms + cosine + exact top-k for node i; writes G row and
//   GT (transpose) via global atomicOr -- kills the separate transpose kernel.
// blocks 512..1535: h = x @ W (independent work, rides the same dispatch).
// Rank count restructured: candidate values in REGISTERS, m scanned via
// float4 LDS broadcasts (128 b128/thread vs 1024 b32 -- the R4 20us hotspot).
__global__ __launch_bounds__(256)
void k_front2(const float* __restrict__ emb, const float* __restrict__ x,
              const float* __restrict__ W, float* __restrict__ h,
              int* __restrict__ idxl, unsigned long long* __restrict__ G,
              unsigned long long* __restrict__ GT) {
    __shared__ SMem sm;
    int t = threadIdx.x;
    if (blockIdx.x >= 512) {                    // ---- h = x @ W ----
        int r0 = ((int)blockIdx.x - 512) * 16;
        ((float4*)sm.g.xs)[t] = ((const float4*)(x + r0*64))[t];
        for (int e = t; e < 1024; e += 256) ((float4*)sm.g.Ws)[e] = ((const float4*)W)[e];
        __syncthreads();
        int row = t >> 4, f0 = (t & 15)*4;
        float ax=0, ay=0, az=0, aw=0;
        #pragma unroll 8
        for (int c = 0; c < 64; ++c) {
            float xv = sm.g.xs[row*64+c];
            float4 wv = *(const float4*)&sm.g.Ws[c*64+f0];
            ax = fmaf(xv,wv.x,ax); ay = fmaf(xv,wv.y,ay);
            az = fmaf(xv,wv.z,az); aw = fmaf(xv,wv.w,aw);
        }
        float4 o; o.x=ax; o.y=ay; o.z=az; o.w=aw;
        ((float4*)(h + r0*64))[t] = o;
        return;
    }
    // ---- front: cosine row + top-k for node i ----
    int i = blockIdx.x;
    if (t < 16) ((float4*)sm.f.ri)[t] = ((const float4*)(emb + i*D))[t];
    if (t < 8) sm.f.gb[t] = 0ull;
    __syncthreads();
    for (int j = t; j < N; j += 256) {          // dot(i,j), |j|^2 in one pass
        const float4* rj = (const float4*)(emb + j*D);
        float dot = 0.f, nsq = 0.f;
        #pragma unroll
        for (int q = 0; q < 16; ++q) {
            float4 v = rj[q];
            float4 u = ((const float4*)sm.f.ri)[q];             // LDS broadcast
            dot = fmaf(u.x,v.x,fmaf(u.y,v.y,fmaf(u.z,v.z,fmaf(u.w,v.w,dot))));
            nsq = fmaf(v.x,v.x,fmaf(v.y,v.y,fmaf(v.z,v.z,fmaf(v.w,v.w,nsq))));
        }
        sm.f.cr[j] = dot; sm.f.q2[j] = nsq;
    }
    __syncthreads();
    float ni = sqrtf(sm.f.q2[i]);
    for (int j = t; j < N; j += 256)
        sm.f.cr[j] = sm.f.cr[j] / (ni*sqrtf(sm.f.q2[j]) + EPSF);
    __syncthreads();
    // exact rank count (jax.lax.top_k tie semantics), values in registers
    float v0 = sm.f.cr[t], v1 = sm.f.cr[t+256];
    int jj1 = t + 256;
    int r0 = 0, r1 = 0;
    const float4* c4 = (const float4*)sm.f.cr;
    #pragma unroll 4
    for (int m4 = 0; m4 < 128; ++m4) {
        float4 u = c4[m4];                       // broadcast: all lanes same addr
        int mb = m4 << 2;
        r0 += (u.x > v0) || (u.x == v0 && mb     < t);
        r0 += (u.y > v0) || (u.y == v0 && mb+1   < t);
        r0 += (u.z > v0) || (u.z == v0 && mb+2   < t);
        r0 += (u.w > v0) || (u.w == v0 && mb+3   < t);
        r1 += (u.x > v1) || (u.x == v1 && mb     < jj1);
        r1 += (u.y > v1) || (u.y == v1 && mb+1   < jj1);
        r1 += (u.z > v1) || (u.z == v1 && mb+2   < jj1);
        r1 += (u.w > v1) || (u.w == v1 && mb+3   < jj1);
    }
    if (r0 < TOPK) {
        idxl[i*KP + r0] = t;                     // rank order == ref order
        atomicOr(&sm.f.gb[t>>6], 1ull << (t&63));
        atomicOr(&GT[t*8 + (i>>6)], 1ull << (i&63));
    }
    if (r1 < TOPK) {
        idxl[i*KP + r1] = jj1;
        atomicOr(&sm.f.gb[jj1>>6], 1ull << (jj1&63));
        atomicOr(&GT[jj1*8 + (i>>6)], 1ull << (i&63));
    }
    __syncthreads();
    if (t < 8) G[i*8+t] = sm.f.gb[t];
}

// Per-edge popcount weights; nb rows built on the fly as G|GT|self
// (all L1/L2-resident, 32KB each). Stores c^2*rs_i; rs_i = 1/sqrt(sum c^2).
__global__ __launch_bounds__(256)
void k_edge2(const unsigned long long* __restrict__ G,
             const unsigned long long* __restrict__ GT,
             const int* __restrict__ idxl,
             float* __restrict__ wgtl, float* __restrict__ rs) {
    __shared__ unsigned long long ni[8];
    __shared__ float red[4];
    __shared__ float rsb;
    int i = blockIdx.x, k = threadIdx.x;
    if (k < 8) {
        unsigned long long v = G[i*8+k] | GT[i*8+k];
        if ((i>>6) == k) v |= 1ull << (i&63);    // self loop
        ni[k] = v;
    }
    __syncthreads();
    float c2 = 0.f;
    if (k < TOPK) {
        int j = idxl[i*KP+k];
        int jw = j >> 6; unsigned long long jb = 1ull << (j&63);
        int c = 0;
        #pragma unroll
        for (int w = 0; w < 8; ++w) {
            unsigned long long nj = G[j*8+w] | GT[j*8+w];
            if (w == jw) nj |= jb;               // self loop (compile-time w)
            c += __popcll(ni[w] & nj);
        }
        c2 = (float)(c*c);                       // edge always has c>=2
    }
    float s = c2;
    #pragma unroll
    for (int o = 32; o > 0; o >>= 1) s += __shfl_down(s, o, 64);
    if ((k & 63) == 0) red[k>>6] = s;
    __syncthreads();
    if (k == 0) {
        float deg = red[0]+red[1]+red[2]+red[3]; // > 0 always
        float r = (float)(1.0/sqrt((double)deg));
        rsb = r; rs[i] = r;
    }
    __syncthreads();
    if (k < TOPK) wgtl[i*KP+k] = c2 * rsb;
}

// h[b] staged in LDS (conflict-free b128 gather); indices/weights read from
// global (wave-broadcast, L2-hot); final weight = wn[k] * rs[j] on the fly.
__global__ __launch_bounds__(512)
void k_agg3(const float* __restrict__ h, const int* __restrict__ idxl,
            const float* __restrict__ wn, const float* __restrict__ rs,
            const float* __restrict__ bias, float* __restrict__ out) {
    __shared__ float4 hs4[512*16];   // 128KB: h[b] staged
    int chunk = blockIdx.x, b = blockIdx.y, t = threadIdx.x;
    const float4* hb = (const float4*)h + b*8192;
    for (int e = t; e < 8192; e += 512) hs4[e] = hb[e];
    int lane = t & 63, wv = t >> 6;
    int ts = lane >> 4, fq = lane & 15;
    int tl = wv*4 + ts;              // local target 0..31
    float4 bv = ((const float4*)bias)[fq];
    __syncthreads();
    #pragma unroll
    for (int grp = 0; grp < 2; ++grp) {
        int ti = chunk*64 + grp*32 + tl;
        const int*   ip = &idxl[ti*KP];
        const float* wp = &wn[ti*KP];
        float ax=0, ay=0, az=0, aw=0;
        #pragma unroll 4
        for (int kk = 0; kk < TOPK; ++kk) {
            int j = ip[kk];
            float w = wp[kk] * rs[j];
            float4 hv = hs4[j*16 + fq];
            ax = fmaf(w,hv.x,ax); ay = fmaf(w,hv.y,ay);
            az = fmaf(w,hv.z,az); aw = fmaf(w,hv.w,aw);
        }
        float4 o; o.x = ax+bv.x; o.y = ay+bv.y; o.z = az+bv.z; o.w = aw+bv.w;
        ((float4*)out)[(b*512 + ti)*16 + fq] = o;
    }
}

extern "C" void kernel_launch(void* const* d_in, const int* in_sizes, int n_in,
                              void* d_out, int out_size, void* d_ws, size_t ws_size,
                              hipStream_t stream) {
    const float* x    = (const float*)d_in[0];   // [32,512,64]
    const float* W    = (const float*)d_in[1];   // [64,64]
    const float* bias = (const float*)d_in[2];   // [64]
    const float* emb  = (const float*)d_in[3];   // [512,64]
    float* out = (float*)d_out;

    char* ws = (char*)d_ws;
    unsigned long long* G  = (unsigned long long*)(ws + 0x100000);
    unsigned long long* GT = (unsigned long long*)(ws + 0x108000);
    int*   idxl = (int*)(ws + 0x110000);
    float* wgtl = (float*)(ws + 0x160000);
    float* rs   = (float*)(ws + 0x1B0000);
    float* h    = (float*)(ws + 0x1C0000);

    hipMemsetAsync(GT, 0, N*8*sizeof(unsigned long long), stream);
    k_front2<<<512 + BN/16, 256, 0, stream>>>(emb, x, W, h, idxl, G, GT);
    k_edge2<<<N, 256, 0, stream>>>(G, GT, idxl, wgtl, rs);
    k_agg3<<<dim3(8, NB), 512, 0, stream>>>(h, idxl, wgtl, rs, bias, out);
}

// Round 7
// 75.185 us; speedup vs baseline: 2.2591x; 1.2197x over previous
//
#include <hip/hip_runtime.h>

#define N 512
#define TOPK 153
#define KP 160
#define D 64
#define NB 32          // batches
#define BN (NB*N)
#define EPSF 1e-8f

// ---------------- ws layout (bytes) ----------------
// 0x100000: G    u64[N*8]        (32KB)  gated selection bitmask (target-major)
// 0x108000: GT   u64[N*8]        (32KB)  transpose bitmask (built via atomicOr)
// 0x110000: idxl i32[N*KP]       (320KB) top-k source ids per target (rank order)
// 0x160000: wgtl f32[N*KP]       (320KB) c^2 * rs_i  (row-scaled structural coeff)
// 0x1B0000: rs   f32[N]          1/sqrt(sum_k c_ik^2)   [max_common cancels]
// 0x1C0000: h    f32[BN*D]       (4MB)

union SMem {
    struct {                     // front blocks (~8.5KB)
        float cr[N];
        float q2[N];
        unsigned long long keys[N];
        float ri[D];
    } f;
    struct { float xs[16*64]; float Ws[64*64]; } g;   // GEMM blocks (20KB)
};

// blocks 0..511: cosine row + exact top-k for node i (u64 sortable keys:
//   (u>v)||(u==v&&m<j)  <=>  key_m > key_j, 2 VALU inst per compare vs ~6).
//   G written via wave ballot (no LDS atomics -- R6's 2.29M conflict cycles).
// blocks 512..1535: h = x @ W rides the same dispatch.
__global__ __launch_bounds__(256)
void k_front3(const float* __restrict__ emb, const float* __restrict__ x,
              const float* __restrict__ W, float* __restrict__ h,
              int* __restrict__ idxl, unsigned long long* __restrict__ G,
              unsigned long long* __restrict__ GT) {
    __shared__ SMem sm;
    int t = threadIdx.x;
    if (blockIdx.x >= 512) {                    // ---- h = x @ W ----
        int r0 = ((int)blockIdx.x - 512) * 16;
        ((float4*)sm.g.xs)[t] = ((const float4*)(x + r0*64))[t];
        for (int e = t; e < 1024; e += 256) ((float4*)sm.g.Ws)[e] = ((const float4*)W)[e];
        __syncthreads();
        int row = t >> 4, f0 = (t & 15)*4;
        float ax=0, ay=0, az=0, aw=0;
        #pragma unroll 8
        for (int c = 0; c < 64; ++c) {
            float xv = sm.g.xs[row*64+c];
            float4 wv = *(const float4*)&sm.g.Ws[c*64+f0];
            ax = fmaf(xv,wv.x,ax); ay = fmaf(xv,wv.y,ay);
            az = fmaf(xv,wv.z,az); aw = fmaf(xv,wv.w,aw);
        }
        float4 o; o.x=ax; o.y=ay; o.z=az; o.w=aw;
        ((float4*)(h + r0*64))[t] = o;
        return;
    }
    // ---- front: cosine row + top-k for node i ----
    int i = blockIdx.x;
    if (t < 16) ((float4*)sm.f.ri)[t] = ((const float4*)(emb + i*D))[t];
    __syncthreads();
    for (int j = t; j < N; j += 256) {          // dot(i,j), |j|^2 in one pass
        const float4* rj = (const float4*)(emb + j*D);
        float dot = 0.f, nsq = 0.f;
        #pragma unroll
        for (int q = 0; q < 16; ++q) {
            float4 v = rj[q];
            float4 u = ((const float4*)sm.f.ri)[q];             // LDS broadcast
            dot = fmaf(u.x,v.x,fmaf(u.y,v.y,fmaf(u.z,v.z,fmaf(u.w,v.w,dot))));
            nsq = fmaf(v.x,v.x,fmaf(v.y,v.y,fmaf(v.z,v.z,fmaf(v.w,v.w,nsq))));
        }
        sm.f.cr[j] = dot; sm.f.q2[j] = nsq;
    }
    __syncthreads();
    // cosine + sortable key build: monotonic float->u32, index in low 9 bits
    float ni = sqrtf(sm.f.q2[i]);
    for (int j = t; j < N; j += 256) {
        float c = sm.f.cr[j] / (ni*sqrtf(sm.f.q2[j]) + EPSF);
        unsigned u = __float_as_uint(c);
        unsigned s = (u >> 31) ? ~u : (u | 0x80000000u);
        sm.f.keys[j] = ((unsigned long long)s << 9) | (unsigned)(511 - j);
    }
    __syncthreads();
    // exact rank via key count: rank_j = #{m : key_m > key_j}
    unsigned long long k0 = sm.f.keys[t], k1 = sm.f.keys[t+256];
    int r0 = 0, r1 = 0;
    const ulonglong2* k2 = (const ulonglong2*)sm.f.keys;
    #pragma unroll 4
    for (int m2 = 0; m2 < 256; ++m2) {
        ulonglong2 km = k2[m2];                  // broadcast: same addr all lanes
        r0 += (km.x > k0); r0 += (km.y > k0);
        r1 += (km.x > k1); r1 += (km.y > k1);
    }
    bool s0 = r0 < TOPK, s1 = r1 < TOPK;
    if (s0) {
        idxl[i*KP + r0] = t;                     // rank order == ref order
        atomicOr(&GT[t*8 + (i>>6)], 1ull << (i&63));
    }
    if (s1) {
        idxl[i*KP + r1] = t + 256;
        atomicOr(&GT[(t+256)*8 + (i>>6)], 1ull << (i&63));
    }
    // G row via ballot: wave w owns candidate words w (t) and w+4 (t+256)
    unsigned long long b0 = __ballot(s0);
    unsigned long long b1 = __ballot(s1);
    int lane = t & 63, w = t >> 6;
    if (lane == 0) {
        G[i*8 + w]     = b0;
        G[i*8 + 4 + w] = b1;
    }
}

// Per-edge popcount weights; nb rows built on the fly as G|GT|self
// (all L1/L2-resident, 32KB each). Stores c^2*rs_i; rs_i = 1/sqrt(sum c^2).
__global__ __launch_bounds__(256)
void k_edge2(const unsigned long long* __restrict__ G,
             const unsigned long long* __restrict__ GT,
             const int* __restrict__ idxl,
             float* __restrict__ wgtl, float* __restrict__ rs) {
    __shared__ unsigned long long ni[8];
    __shared__ float red[4];
    __shared__ float rsb;
    int i = blockIdx.x, k = threadIdx.x;
    if (k < 8) {
        unsigned long long v = G[i*8+k] | GT[i*8+k];
        if ((i>>6) == k) v |= 1ull << (i&63);    // self loop
        ni[k] = v;
    }
    __syncthreads();
    float c2 = 0.f;
    if (k < TOPK) {
        int j = idxl[i*KP+k];
        int jw = j >> 6; unsigned long long jb = 1ull << (j&63);
        int c = 0;
        #pragma unroll
        for (int w = 0; w < 8; ++w) {
            unsigned long long nj = G[j*8+w] | GT[j*8+w];
            if (w == jw) nj |= jb;               // self loop (compile-time w)
            c += __popcll(ni[w] & nj);
        }
        c2 = (float)(c*c);                       // edge always has c>=2
    }
    float s = c2;
    #pragma unroll
    for (int o = 32; o > 0; o >>= 1) s += __shfl_down(s, o, 64);
    if ((k & 63) == 0) red[k>>6] = s;
    __syncthreads();
    if (k == 0) {
        float deg = red[0]+red[1]+red[2]+red[3]; // > 0 always
        float r = (float)(1.0/sqrt((double)deg));
        rsb = r; rs[i] = r;
    }
    __syncthreads();
    if (k < TOPK) wgtl[i*KP+k] = c2 * rsb;
}

// h[b] staged in LDS (conflict-free b128 gather); indices/weights read from
// global (wave-broadcast, L2-hot); final weight = wn[k] * rs[j] on the fly.
__global__ __launch_bounds__(512)
void k_agg3(const float* __restrict__ h, const int* __restrict__ idxl,
            const float* __restrict__ wn, const float* __restrict__ rs,
            const float* __restrict__ bias, float* __restrict__ out) {
    __shared__ float4 hs4[512*16];   // 128KB: h[b] staged
    int chunk = blockIdx.x, b = blockIdx.y, t = threadIdx.x;
    const float4* hb = (const float4*)h + b*8192;
    for (int e = t; e < 8192; e += 512) hs4[e] = hb[e];
    int lane = t & 63, wv = t >> 6;
    int ts = lane >> 4, fq = lane & 15;
    int tl = wv*4 + ts;              // local target 0..31
    float4 bv = ((const float4*)bias)[fq];
    __syncthreads();
    #pragma unroll
    for (int grp = 0; grp < 2; ++grp) {
        int ti = chunk*64 + grp*32 + tl;
        const int*   ip = &idxl[ti*KP];
        const float* wp = &wn[ti*KP];
        float ax=0, ay=0, az=0, aw=0;
        #pragma unroll 4
        for (int kk = 0; kk < TOPK; ++kk) {
            int j = ip[kk];
            float w = wp[kk] * rs[j];
            float4 hv = hs4[j*16 + fq];
            ax = fmaf(w,hv.x,ax); ay = fmaf(w,hv.y,ay);
            az = fmaf(w,hv.z,az); aw = fmaf(w,hv.w,aw);
        }
        float4 o; o.x = ax+bv.x; o.y = ay+bv.y; o.z = az+bv.z; o.w = aw+bv.w;
        ((float4*)out)[(b*512 + ti)*16 + fq] = o;
    }
}

extern "C" void kernel_launch(void* const* d_in, const int* in_sizes, int n_in,
                              void* d_out, int out_size, void* d_ws, size_t ws_size,
                              hipStream_t stream) {
    const float* x    = (const float*)d_in[0];   // [32,512,64]
    const float* W    = (const float*)d_in[1];   // [64,64]
    const float* bias = (const float*)d_in[2];   // [64]
    const float* emb  = (const float*)d_in[3];   // [512,64]
    float* out = (float*)d_out;

    char* ws = (char*)d_ws;
    unsigned long long* G  = (unsigned long long*)(ws + 0x100000);
    unsigned long long* GT = (unsigned long long*)(ws + 0x108000);
    int*   idxl = (int*)(ws + 0x110000);
    float* wgtl = (float*)(ws + 0x160000);
    float* rs   = (float*)(ws + 0x1B0000);
    float* h    = (float*)(ws + 0x1C0000);

    hipMemsetAsync(GT, 0, N*8*sizeof(unsigned long long), stream);
    k_front3<<<512 + BN/16, 256, 0, stream>>>(emb, x, W, h, idxl, G, GT);
    k_edge2<<<N, 256, 0, stream>>>(G, GT, idxl, wgtl, rs);
    k_agg3<<<dim3(8, NB), 512, 0, stream>>>(h, idxl, wgtl, rs, bias, out);
}